// Round 3
// baseline (1510.478 us; speedup 1.0000x reference)
//
#include <hip/hip_runtime.h>

// Fused 3x3 SAME conv + bias + ReLU + 2x2 maxpool.
// Block covers a PH x PW pooled tile (PH*PW == NT threads) for OCB output
// channels of one batch image. Input staged in LDS in IC chunks of ICCH.
// Each thread computes 4 conv pixels (its 2x2 pool window) x OCB channels.
template<int PH, int PW, int OCB, int ICCH, int NT>
__global__ __launch_bounds__(NT)
void conv_relu_pool(const float* __restrict__ in, const float* __restrict__ wt,
                    const float* __restrict__ bias, float* __restrict__ out,
                    int C, int H, int W, int OC) {
  constexpr int TR = 2 * PH + 2;          // tile rows (conv rows + halo)
  constexpr int TC = 2 * PW + 2;          // tile cols (full width + halo)
  constexpr int STR = TC + 1;             // odd stride -> fewer bank conflicts
  __shared__ float sIn[ICCH * TR * STR];

  const int tid = threadIdx.x;
  const int pw = tid % PW;
  const int ph = tid / PW;
  const int n = blockIdx.z;
  const int oc0 = blockIdx.y * OCB;
  const int ph0 = blockIdx.x * PH;        // pooled row base
  const int r0 = ph0 * 2;                 // conv/input row base (tile r=0 -> input row r0-1)
  const int HW = H * W;
  const float* inN = in + (size_t)n * C * HW;

  float acc[OCB][4];
#pragma unroll
  for (int o = 0; o < OCB; ++o) {
    acc[o][0] = 0.f; acc[o][1] = 0.f; acc[o][2] = 0.f; acc[o][3] = 0.f;
  }

  for (int c0 = 0; c0 < C; c0 += ICCH) {
    // ---- stage ICCH input channels of the (TR x TC) halo tile into LDS ----
    constexpr int TOT = ICCH * TR * TC;
    for (int t = tid; t < TOT; t += NT) {
      const int ic  = t / (TR * TC);
      const int rem = t - ic * (TR * TC);
      const int r   = rem / TC;
      const int cc  = rem - r * TC;
      const int ri = r0 + r - 1;
      const int ci = cc - 1;
      float v = 0.f;
      if (ri >= 0 && ri < H && ci >= 0 && ci < W)
        v = inN[(size_t)(c0 + ic) * HW + (size_t)ri * W + ci];
      sIn[(ic * TR + r) * STR + cc] = v;
    }
    __syncthreads();

    // ---- compute ----
    for (int icl = 0; icl < ICCH; ++icl) {
      float xv[4][4];
#pragma unroll
      for (int i = 0; i < 4; ++i)
#pragma unroll
        for (int j = 0; j < 4; ++j)
          xv[i][j] = sIn[(icl * TR + 2 * ph + i) * STR + 2 * pw + j];

      const float* wbase = wt + ((size_t)oc0 * C + (size_t)(c0 + icl)) * 9;
#pragma unroll
      for (int o = 0; o < OCB; ++o) {
        const float* wp = wbase + (size_t)o * C * 9;   // uniform address -> s_load
#pragma unroll
        for (int kh = 0; kh < 3; ++kh) {
#pragma unroll
          for (int kw = 0; kw < 3; ++kw) {
            const float wv = wp[kh * 3 + kw];
            acc[o][0] = fmaf(xv[kh][kw],         wv, acc[o][0]);
            acc[o][1] = fmaf(xv[kh][kw + 1],     wv, acc[o][1]);
            acc[o][2] = fmaf(xv[kh + 1][kw],     wv, acc[o][2]);
            acc[o][3] = fmaf(xv[kh + 1][kw + 1], wv, acc[o][3]);
          }
        }
      }
    }
    __syncthreads();
  }

  // ---- bias + relu + 2x2 maxpool + store ----
  const int PHo = H >> 1, PWo = W >> 1;
  float* outN = out + ((size_t)n * OC + oc0) * PHo * PWo;
#pragma unroll
  for (int o = 0; o < OCB; ++o) {
    const float b = bias[oc0 + o];
    float m = fmaxf(fmaxf(acc[o][0], acc[o][1]), fmaxf(acc[o][2], acc[o][3]));
    m = fmaxf(m + b, 0.f);
    outN[(size_t)o * PHo * PWo + (size_t)(ph0 + ph) * PWo + pw] = m;
  }
}

// Fused FC1(4096->128)+ReLU+FC2 head. The 200-step scan collapses:
// fx = px + 20*vx = h . (wl2[0] + 20*wl2[2]) + (bl2[0] + 20*bl2[2]).
// One block per batch row; 256 threads = 128 outputs x 2 K-halves.
__global__ __launch_bounds__(256)
void fc_head(const float* __restrict__ h4, const float* __restrict__ wl1,
             const float* __restrict__ bl1, const float* __restrict__ wl2,
             const float* __restrict__ bl2, float* __restrict__ out) {
  __shared__ float row[4096];
  __shared__ float red[256];
  const int tid = threadIdx.x;
  const int b = blockIdx.x;
  {
    const float4* src = (const float4*)(h4 + (size_t)b * 4096);
    float4* dst = (float4*)row;
    for (int t = tid; t < 1024; t += 256) dst[t] = src[t];
  }
  __syncthreads();

  const int nn = tid & 127;
  const int half = tid >> 7;
  const float4* wrow = (const float4*)(wl1 + (size_t)nn * 4096) + half * 512;
  const float4* xrow = (const float4*)row + half * 512;
  float a0 = 0.f, a1 = 0.f, a2 = 0.f, a3 = 0.f;
  for (int k = 0; k < 512; k += 4) {
    float4 w0 = wrow[k + 0], x0 = xrow[k + 0];
    float4 w1 = wrow[k + 1], x1 = xrow[k + 1];
    float4 w2 = wrow[k + 2], x2 = xrow[k + 2];
    float4 w3 = wrow[k + 3], x3 = xrow[k + 3];
    a0 = fmaf(w0.x, x0.x, fmaf(w0.y, x0.y, fmaf(w0.z, x0.z, fmaf(w0.w, x0.w, a0))));
    a1 = fmaf(w1.x, x1.x, fmaf(w1.y, x1.y, fmaf(w1.z, x1.z, fmaf(w1.w, x1.w, a1))));
    a2 = fmaf(w2.x, x2.x, fmaf(w2.y, x2.y, fmaf(w2.z, x2.z, fmaf(w2.w, x2.w, a2))));
    a3 = fmaf(w3.x, x3.x, fmaf(w3.y, x3.y, fmaf(w3.z, x3.z, fmaf(w3.w, x3.w, a3))));
  }
  red[tid] = (a0 + a1) + (a2 + a3);
  __syncthreads();

  float contrib = 0.f;
  if (tid < 128) {
    float hsum = red[tid] + red[tid + 128] + bl1[tid];
    hsum = fmaxf(hsum, 0.f);
    contrib = hsum * (wl2[tid] + 20.0f * wl2[256 + tid]);
  }
  __syncthreads();
  red[tid] = contrib;
  __syncthreads();
#pragma unroll
  for (int s = 128; s > 0; s >>= 1) {
    if (tid < s) red[tid] += red[tid + s];
    __syncthreads();
  }
  if (tid == 0) out[b] = red[0] + bl2[0] + 20.0f * bl2[2];
}

extern "C" void kernel_launch(void* const* d_in, const int* in_sizes, int n_in,
                              void* d_out, int out_size, void* d_ws, size_t ws_size,
                              hipStream_t stream) {
  const float* x   = (const float*)d_in[0];
  const float* w1  = (const float*)d_in[1];
  const float* b1  = (const float*)d_in[2];
  const float* w2  = (const float*)d_in[3];
  const float* b2  = (const float*)d_in[4];
  const float* w3  = (const float*)d_in[5];
  const float* b3  = (const float*)d_in[6];
  const float* w4  = (const float*)d_in[7];
  const float* b4  = (const float*)d_in[8];
  const float* wl1 = (const float*)d_in[9];
  const float* bl1 = (const float*)d_in[10];
  const float* wl2 = (const float*)d_in[11];
  const float* bl2 = (const float*)d_in[12];
  float* out = (float*)d_out;
  float* ws  = (float*)d_ws;

  // Workspace layout (floats). Peak = 192 MiB.
  float* h1 = ws;                 // 256*32*64*64 = 33,554,432 f
  float* h2 = ws + 33554432;      // 256*64*32*32 = 16,777,216 f
  float* h3 = ws;                 // 256*64*16*16 =  4,194,304 f (reuses h1 space)
  float* h4 = ws + 4194304;       // 256*64*8*8   =  1,048,576 f (after h3)

  // conv1: (256,12,128,128) -> (256,32,64,64)
  conv_relu_pool<4, 64, 16, 6, 256><<<dim3(16, 2, 256), 256, 0, stream>>>(
      x, w1, b1, h1, 12, 128, 128, 32);
  // conv2: (256,32,64,64) -> (256,64,32,32)
  conv_relu_pool<8, 32, 16, 8, 256><<<dim3(4, 4, 256), 256, 0, stream>>>(
      h1, w2, b2, h2, 32, 64, 64, 64);
  // conv3: (256,64,32,32) -> (256,64,16,16)
  conv_relu_pool<16, 16, 16, 8, 256><<<dim3(1, 4, 256), 256, 0, stream>>>(
      h2, w3, b3, h3, 64, 32, 32, 64);
  // conv4: (256,64,16,16) -> (256,64,8,8)
  conv_relu_pool<8, 8, 16, 16, 64><<<dim3(1, 4, 256), 64, 0, stream>>>(
      h3, w4, b4, h4, 64, 16, 16, 64);
  // FC head + collapsed physics scan
  fc_head<<<256, 256, 0, stream>>>(h4, wl1, bl1, wl2, bl2, out);
}

// Round 4
// 357.907 us; speedup vs baseline: 4.2203x; 4.2203x over previous
//
#include <hip/hip_runtime.h>

// MFMA f16 conv pipeline.
// Activations NHWC f16; weights pre-packed into A-fragment order.
// mfma_f32_16x16x32_f16 layouts (CDNA4):
//   A[m][k]: m = lane&15, k = (lane>>4)*8 + j   (j=0..7, 4 VGPRs)
//   B[k][n]: n = lane&15, k = (lane>>4)*8 + j
//   D[m][n]: n = lane&15, m = (lane>>4)*4 + reg (verified learn_hip m89)
// Conv as 9 shifted GEMMs (k=ic) for conv2-4; conv1 full-im2col k=160
// (kh*48 + kw*16 + ic, ic padded 12->16, k>=144 zero-weighted).
// Fused 2x2 maxpool + bias + relu epilogue (rows in-reg, cols via shfl_xor 1).

typedef _Float16 f16;
typedef _Float16 f16x8 __attribute__((ext_vector_type(8)));
typedef _Float16 f16x4 __attribute__((ext_vector_type(4)));
typedef float f32x4 __attribute__((ext_vector_type(4)));

// ---------------- weight pre-pack ----------------
// Apack frags (1024B each = [lane][j] f16): conv1: 10 (ks*2+og); conv2: 36 at
// base 10 ((sh)*4+og); conv3: 72 at 46 ((sh*2+ks)*4+og); conv4: 72 at 118.
__global__ __launch_bounds__(512)
void pack_weights(const float* __restrict__ w1, const float* __restrict__ w2,
                  const float* __restrict__ w3, const float* __restrict__ w4,
                  f16* __restrict__ apack) {
  int idx = blockIdx.x * 512 + threadIdx.x;   // 190*512 total
  int frag = idx >> 9;
  int e = idx & 511;
  int lane = e >> 3, j = e & 7;
  int row16 = lane & 15, kg = lane >> 4;
  float v = 0.f;
  if (frag < 10) {
    int ks = frag >> 1, og = frag & 1;
    int oc = og * 16 + row16;
    int k = ks * 32 + kg * 8 + j;
    if (k < 144) {
      int kh = k / 48, rem = k % 48, kw = rem >> 4, ic = rem & 15;
      if (ic < 12) v = w1[((oc * 12 + ic) * 3 + kh) * 3 + kw];
    }
  } else if (frag < 46) {
    int f = frag - 10;
    int sh = f >> 2, og = f & 3;
    int kh = sh / 3, kw = sh % 3;
    int oc = og * 16 + row16;
    int ic = kg * 8 + j;
    v = w2[((oc * 32 + ic) * 3 + kh) * 3 + kw];
  } else {
    const float* w = (frag < 118) ? w3 : w4;
    int f = frag - ((frag < 118) ? 46 : 118);
    int sk = f >> 2, og = f & 3;
    int sh = sk >> 1, ks = sk & 1;
    int kh = sh / 3, kw = sh % 3;
    int oc = og * 16 + row16;
    int ic = ks * 32 + kg * 8 + j;
    v = w[((oc * 64 + ic) * 3 + kh) * 3 + kw];
  }
  apack[idx] = (f16)v;
}

// ---------------- conv1: 12ch fp32 NCHW -> 32ch NHWC f16, pool ----------------
// Block: 4 conv rows (2 pooled) x 128 px, 8 waves (wave: 2 rows x 32 px).
__global__ __launch_bounds__(512)
void conv1_mfma(const float* __restrict__ x, const f16* __restrict__ apack,
                const float* __restrict__ bias, f16* __restrict__ hout) {
  constexpr int W = 128, H = 128;
  constexpr int SR = 7, PADB = 32, ROWB = 130 * PADB;  // 4160 B/row-slot
  __shared__ char smem[SR * ROWB];                     // 29120 B
  const int tid = threadIdx.x;
  const int n = blockIdx.y;
  const int r0 = blockIdx.x * 4;
  // zero-fill (halos, ic pad)
  for (int t = tid; t < SR * ROWB / 16; t += 512)
    *(float4*)(smem + t * 16) = make_float4(0.f, 0.f, 0.f, 0.f);
  __syncthreads();
  // stage real data: transpose NCHW fp32 -> [slot][px][ic] f16
  for (int t = tid; t < 12 * 7 * 32; t += 512) {
    int ic = t / 224;
    int rem = t - ic * 224;
    int sr = rem >> 5;
    int pc = rem & 31;              // 4-px chunk
    int ri = r0 + sr - 1;
    if (ri >= 0 && ri < H) {
      float4 v = *(const float4*)(x + ((size_t)(n * 12 + ic) * H + ri) * W + pc * 4);
      char* d = smem + sr * ROWB + (pc * 4 + 1) * PADB + ic * 2;
      *(f16*)(d)      = (f16)v.x;
      *(f16*)(d + 32) = (f16)v.y;
      *(f16*)(d + 64) = (f16)v.z;
      *(f16*)(d + 96) = (f16)v.w;
    }
  }
  __syncthreads();

  const int wv = tid >> 6, l = tid & 63;
  const int rp = wv >> 2;                // pooled row within block (0..1)
  const int pxb = (wv & 3) * 32;
  const int rl0 = rp * 2;
  const int lp = l & 15, kg = l >> 4;

  f16x8 A[5][2];
#pragma unroll
  for (int ks = 0; ks < 5; ++ks)
#pragma unroll
    for (int og = 0; og < 2; ++og)
      A[ks][og] = *(const f16x8*)(apack + (((ks * 2 + og) << 9) + (l << 3)));

  f32x4 acc[2][2][2];
#pragma unroll
  for (int a = 0; a < 2; ++a)
#pragma unroll
    for (int b = 0; b < 2; ++b)
#pragma unroll
      for (int c = 0; c < 2; ++c)
        acc[a][b][c] = (f32x4){0.f, 0.f, 0.f, 0.f};

#pragma unroll
  for (int rowi = 0; rowi < 2; ++rowi) {
#pragma unroll
    for (int pg = 0; pg < 2; ++pg) {
      const int p = pxb + pg * 16 + lp;
#pragma unroll
      for (int ks = 0; ks < 5; ++ks) {
        const int c8 = ks * 4 + kg;
        const int ro = c8 / 6;
        const int o48 = (c8 - ro * 6) * 8;
        const int pxo = o48 >> 4;
        const int icb = o48 & 15;
        const int slot = rl0 + rowi + ro;          // <= 6
        f16x8 B = *(const f16x8*)(smem + slot * ROWB + (p + pxo) * PADB + icb * 2);
#pragma unroll
        for (int og = 0; og < 2; ++og)
          acc[rowi][pg][og] =
              __builtin_amdgcn_mfma_f32_16x16x32_f16(A[ks][og], B, acc[rowi][pg][og], 0, 0, 0);
      }
    }
  }
  // epilogue: pool 2x2, bias, relu, NHWC f16 store (OC=32)
  const int pr = blockIdx.x * 2 + rp;
#pragma unroll
  for (int pg = 0; pg < 2; ++pg) {
#pragma unroll
    for (int og = 0; og < 2; ++og) {
      float v[4];
#pragma unroll
      for (int c = 0; c < 4; ++c) {
        float m = fmaxf(acc[0][pg][og][c], acc[1][pg][og][c]);
        v[c] = fmaxf(m, __shfl_xor(m, 1));
      }
      if ((l & 1) == 0) {
        const int pw = (pxb + pg * 16 + lp) >> 1;
        const int oc0 = og * 16 + kg * 4;
        f16x4 pk;
#pragma unroll
        for (int c = 0; c < 4; ++c)
          pk[c] = (f16)fmaxf(v[c] + bias[oc0 + c], 0.f);
        *(f16x4*)(hout + (((size_t)(n * 64 + pr) * 64 + pw) * 32 + oc0)) = pk;
      }
    }
  }
}

// ---------------- conv2/3/4: NHWC f16 -> NHWC f16 (or NCHW f32), pool ----------
// 9-shift GEMM, OC=64 (4 ocg). Wave: 2 conv rows x (16*PGn) px. 4 waves/block.
template<int C, int W, int H, int BR, int KS, int PADB, int PGn, bool NCHW_OUT>
__global__ __launch_bounds__(256)
void conv_shift(const f16* __restrict__ hin, const f16* __restrict__ apack,
                const float* __restrict__ bias, void* __restrict__ hout) {
  constexpr int SR = BR + 2;
  constexpr int ROWB = (W + 2) * PADB;
  __shared__ char smem[SR * ROWB];
  const int tid = threadIdx.x;
  const int n = blockIdx.y;
  const int r0 = blockIdx.x * BR;
  constexpr int CPC = C / 8;                     // 16B chunks per pixel
  constexpr int TOTC = SR * (W + 2) * CPC;
  for (int t = tid; t < TOTC; t += 256) {
    int sr = t / ((W + 2) * CPC);
    int rem = t - sr * ((W + 2) * CPC);
    int px = rem / CPC;
    int kc = rem - px * CPC;
    int ri = r0 + sr - 1;
    int gx = px - 1;
    float4 v = make_float4(0.f, 0.f, 0.f, 0.f);
    if (ri >= 0 && ri < H && gx >= 0 && gx < W)
      v = *(const float4*)(hin + (((size_t)(n * H + ri) * W + gx) * C + kc * 8));
    *(float4*)(smem + sr * ROWB + px * PADB + kc * 16) = v;
  }
  __syncthreads();

  const int wv = tid >> 6, l = tid & 63;
  constexpr int WPP = W / (16 * PGn);            // waves per pooled row
  const int rp = wv / WPP;
  const int pxb = (wv % WPP) * 16 * PGn;
  const int rl0 = rp * 2;
  const int lp = l & 15, kg = l >> 4;
  const int px0 = pxb + lp;

  f32x4 acc[2][PGn][4];
#pragma unroll
  for (int a = 0; a < 2; ++a)
#pragma unroll
    for (int b = 0; b < PGn; ++b)
#pragma unroll
      for (int c = 0; c < 4; ++c)
        acc[a][b][c] = (f32x4){0.f, 0.f, 0.f, 0.f};

  for (int sh = 0; sh < 9; ++sh) {
    const int kh = sh / 3, kw = sh % 3;
    f16x8 A[KS][4];
#pragma unroll
    for (int ks = 0; ks < KS; ++ks)
#pragma unroll
      for (int og = 0; og < 4; ++og)
        A[ks][og] = *(const f16x8*)(apack + ((((sh * KS + ks) * 4 + og) << 9) + (l << 3)));
#pragma unroll
    for (int rowi = 0; rowi < 2; ++rowi) {
      const char* base = smem + (rl0 + rowi + kh) * ROWB;
#pragma unroll
      for (int pg = 0; pg < PGn; ++pg) {
#pragma unroll
        for (int ks = 0; ks < KS; ++ks) {
          f16x8 B = *(const f16x8*)(base + (px0 + pg * 16 + kw) * PADB + ks * 64 + kg * 16);
#pragma unroll
          for (int og = 0; og < 4; ++og)
            acc[rowi][pg][og] =
                __builtin_amdgcn_mfma_f32_16x16x32_f16(A[ks][og], B, acc[rowi][pg][og], 0, 0, 0);
        }
      }
    }
  }
  // epilogue
  constexpr int PH = H / 2, PW = W / 2;
  const int pr = blockIdx.x * (BR / 2) + rp;
#pragma unroll
  for (int pg = 0; pg < PGn; ++pg) {
#pragma unroll
    for (int og = 0; og < 4; ++og) {
      float v[4];
#pragma unroll
      for (int c = 0; c < 4; ++c) {
        float m = fmaxf(acc[0][pg][og][c], acc[1][pg][og][c]);
        v[c] = fmaxf(m, __shfl_xor(m, 1));
      }
      if ((l & 1) == 0) {
        const int pw = (pxb + pg * 16 + lp) >> 1;
        const int oc0 = og * 16 + kg * 4;
        if constexpr (NCHW_OUT) {
          float* o = (float*)hout;
#pragma unroll
          for (int c = 0; c < 4; ++c)
            o[(((size_t)n * 64 + oc0 + c) * PH + pr) * PW + pw] =
                fmaxf(v[c] + bias[oc0 + c], 0.f);
        } else {
          f16x4 pk;
#pragma unroll
          for (int c = 0; c < 4; ++c)
            pk[c] = (f16)fmaxf(v[c] + bias[oc0 + c], 0.f);
          *(f16x4*)((f16*)hout + (((size_t)(n * PH + pr) * PW + pw) * 64 + oc0)) = pk;
        }
      }
    }
  }
}

// ---------------- FC head (unchanged; scan collapses to fx = h.(wl2_0+20*wl2_2)+...) --
__global__ __launch_bounds__(256)
void fc_head(const float* __restrict__ h4, const float* __restrict__ wl1,
             const float* __restrict__ bl1, const float* __restrict__ wl2,
             const float* __restrict__ bl2, float* __restrict__ out) {
  __shared__ float row[4096];
  __shared__ float red[256];
  const int tid = threadIdx.x;
  const int b = blockIdx.x;
  {
    const float4* src = (const float4*)(h4 + (size_t)b * 4096);
    float4* dst = (float4*)row;
    for (int t = tid; t < 1024; t += 256) dst[t] = src[t];
  }
  __syncthreads();
  const int nn = tid & 127;
  const int half = tid >> 7;
  const float4* wrow = (const float4*)(wl1 + (size_t)nn * 4096) + half * 512;
  const float4* xrow = (const float4*)row + half * 512;
  float a0 = 0.f, a1 = 0.f, a2 = 0.f, a3 = 0.f;
  for (int k = 0; k < 512; k += 4) {
    float4 w0 = wrow[k + 0], x0 = xrow[k + 0];
    float4 w1 = wrow[k + 1], x1 = xrow[k + 1];
    float4 w2 = wrow[k + 2], x2 = xrow[k + 2];
    float4 w3 = wrow[k + 3], x3 = xrow[k + 3];
    a0 = fmaf(w0.x, x0.x, fmaf(w0.y, x0.y, fmaf(w0.z, x0.z, fmaf(w0.w, x0.w, a0))));
    a1 = fmaf(w1.x, x1.x, fmaf(w1.y, x1.y, fmaf(w1.z, x1.z, fmaf(w1.w, x1.w, a1))));
    a2 = fmaf(w2.x, x2.x, fmaf(w2.y, x2.y, fmaf(w2.z, x2.z, fmaf(w2.w, x2.w, a2))));
    a3 = fmaf(w3.x, x3.x, fmaf(w3.y, x3.y, fmaf(w3.z, x3.z, fmaf(w3.w, x3.w, a3))));
  }
  red[tid] = (a0 + a1) + (a2 + a3);
  __syncthreads();
  float contrib = 0.f;
  if (tid < 128) {
    float hsum = red[tid] + red[tid + 128] + bl1[tid];
    hsum = fmaxf(hsum, 0.f);
    contrib = hsum * (wl2[tid] + 20.0f * wl2[256 + tid]);
  }
  __syncthreads();
  red[tid] = contrib;
  __syncthreads();
#pragma unroll
  for (int s = 128; s > 0; s >>= 1) {
    if (tid < s) red[tid] += red[tid + s];
    __syncthreads();
  }
  if (tid == 0) out[b] = red[0] + bl2[0] + 20.0f * bl2[2];
}

extern "C" void kernel_launch(void* const* d_in, const int* in_sizes, int n_in,
                              void* d_out, int out_size, void* d_ws, size_t ws_size,
                              hipStream_t stream) {
  const float* x   = (const float*)d_in[0];
  const float* w1  = (const float*)d_in[1];
  const float* b1  = (const float*)d_in[2];
  const float* w2  = (const float*)d_in[3];
  const float* b2  = (const float*)d_in[4];
  const float* w3  = (const float*)d_in[5];
  const float* b3  = (const float*)d_in[6];
  const float* w4  = (const float*)d_in[7];
  const float* b4  = (const float*)d_in[8];
  const float* wl1 = (const float*)d_in[9];
  const float* bl1 = (const float*)d_in[10];
  const float* wl2 = (const float*)d_in[11];
  const float* bl2 = (const float*)d_in[12];
  float* out = (float*)d_out;
  char* ws = (char*)d_ws;

  // ws layout (bytes): Apack @0 (195KB, reserve 1MB); h1 @1M (64MB NHWC f16);
  // h2 @68,157,440 (32MB); h3 @101,711,872 (8MB); h4 @110,100,480 (4MB f32 NCHW).
  f16* apack = (f16*)ws;
  f16* h1 = (f16*)(ws + (1u << 20));
  f16* h2 = (f16*)(ws + 68157440u);
  f16* h3 = (f16*)(ws + 101711872u);
  float* h4 = (float*)(ws + 110100480u);

  pack_weights<<<190, 512, 0, stream>>>(w1, w2, w3, w4, apack);
  conv1_mfma<<<dim3(32, 256), 512, 0, stream>>>(x, apack, b1, h1);
  conv_shift<32, 64, 64, 4, 1, 64, 2, false><<<dim3(16, 256), 256, 0, stream>>>(
      h1, apack + 10 * 512, b2, (void*)h2);
  conv_shift<64, 32, 32, 8, 2, 144, 2, false><<<dim3(4, 256), 256, 0, stream>>>(
      h2, apack + 46 * 512, b3, (void*)h3);
  conv_shift<64, 16, 16, 8, 2, 144, 1, true><<<dim3(2, 256), 256, 0, stream>>>(
      h3, apack + 118 * 512, b4, (void*)h4);
  fc_head<<<256, 256, 0, stream>>>(h4, wl1, bl1, wl2, bl2, out);
}

// Round 6
// 303.595 us; speedup vs baseline: 4.9753x; 1.1789x over previous
//
#include <hip/hip_runtime.h>

// MFMA f16 conv pipeline, round 5 (resubmitted round 6 — infra failure, no data).
// Round-4 post-mortem: conv1's NCHW->LDS staging used 2B scalar writes at
// 128B lane stride = 32-way bank conflict (8.4e7 conflict cycles = ~137us).
// Fix: register 4x4 shuffle-transpose staging (conflict-free ds_write_b64),
// PADB 32->48B (b128 reads 2-way = free), fc_head occupancy rework.
//
// mfma_f32_16x16x32_f16 layouts (CDNA4):
//   A[m][k]: m = lane&15, k = (lane>>4)*8 + j
//   B[k][n]: n = lane&15, k = (lane>>4)*8 + j
//   D[m][n]: n = lane&15, m = (lane>>4)*4 + reg
// conv1: full-im2col k=160 (kh*48 + kw*16 + ic, ic padded 12->16, k>=144 zero).
// conv2-4: 9 shifted GEMMs (k=ic).

typedef _Float16 f16;
typedef _Float16 f16x8 __attribute__((ext_vector_type(8)));
typedef _Float16 f16x4 __attribute__((ext_vector_type(4)));
typedef float f32x4 __attribute__((ext_vector_type(4)));

// ---------------- weight pre-pack ----------------
__global__ __launch_bounds__(512)
void pack_weights(const float* __restrict__ w1, const float* __restrict__ w2,
                  const float* __restrict__ w3, const float* __restrict__ w4,
                  f16* __restrict__ apack) {
  int idx = blockIdx.x * 512 + threadIdx.x;   // 190*512 total
  int frag = idx >> 9;
  int e = idx & 511;
  int lane = e >> 3, j = e & 7;
  int row16 = lane & 15, kg = lane >> 4;
  float v = 0.f;
  if (frag < 10) {
    int ks = frag >> 1, og = frag & 1;
    int oc = og * 16 + row16;
    int k = ks * 32 + kg * 8 + j;
    if (k < 144) {
      int kh = k / 48, rem = k % 48, kw = rem >> 4, ic = rem & 15;
      if (ic < 12) v = w1[((oc * 12 + ic) * 3 + kh) * 3 + kw];
    }
  } else if (frag < 46) {
    int f = frag - 10;
    int sh = f >> 2, og = f & 3;
    int kh = sh / 3, kw = sh % 3;
    int oc = og * 16 + row16;
    int ic = kg * 8 + j;
    v = w2[((oc * 32 + ic) * 3 + kh) * 3 + kw];
  } else {
    const float* w = (frag < 118) ? w3 : w4;
    int f = frag - ((frag < 118) ? 46 : 118);
    int sk = f >> 2, og = f & 3;
    int sh = sk >> 1, ks = sk & 1;
    int kh = sh / 3, kw = sh % 3;
    int oc = og * 16 + row16;
    int ic = ks * 32 + kg * 8 + j;
    v = w[((oc * 64 + ic) * 3 + kh) * 3 + kw];
  }
  apack[idx] = (f16)v;
}

// ---------------- conv1: 12ch fp32 NCHW -> 32ch NHWC f16, pool ----------------
// Block: 4 conv rows x 128 px, 512 threads (8 waves; wave: 2 conv rows x 32 px).
// Staging: 16-lane groups do a register 4x4 shuffle transpose; writes are
// conflict-free ds_write_b64. LDS pixel stride 48B -> 2-way (free) b128 reads.
__global__ __launch_bounds__(512)
void conv1_mfma(const float* __restrict__ x, const f16* __restrict__ apack,
                const float* __restrict__ bias, f16* __restrict__ hout) {
  constexpr int W = 128, H = 128;
  constexpr int SR = 7, PADB = 48, ROWB = 130 * PADB;  // 6240 B/row-slot
  __shared__ char smem[SR * ROWB];                     // 43680 B
  const int tid = threadIdx.x;
  const int n = blockIdx.y;
  const int r0 = blockIdx.x * 4;

  // zero halo columns (px 0 and 129) only; everything else gets written
  if (tid < 42) {
    int slot = tid / 6, r = tid % 6;
    int px = (r >= 3) ? 129 : 0;
    int ch = r % 3;
    *(float4*)(smem + slot * ROWB + px * PADB + ch * 16) =
        make_float4(0.f, 0.f, 0.f, 0.f);
  }
  // staging: group g (=tid>>4) owns px chunk pc=g (4 px) for all 7 row-slots.
  {
    const int g = tid >> 4;
    const int l16 = tid & 15;
    const int Q = l16 >> 2, q = l16 & 3;     // quad, lane-in-quad
    for (int sr = 0; sr < SR; ++sr) {
      const int ri = r0 + sr - 1;
      float4 a = make_float4(0.f, 0.f, 0.f, 0.f);
      if (l16 < 12 && ri >= 0 && ri < H)
        a = *(const float4*)(x + ((size_t)(n * 12 + l16) * H + ri) * W + g * 4);
      // 4x4 transpose within quad (rows=ic, cols=px) via xor butterfly
      float4 t1, t2;
      {
        float sx = __shfl_xor(a.x, 1), sy = __shfl_xor(a.y, 1);
        float sz = __shfl_xor(a.z, 1), sw = __shfl_xor(a.w, 1);
        bool odd = q & 1;
        t1.x = odd ? sy : a.x;  t1.y = odd ? a.y : sx;
        t1.z = odd ? sw : a.z;  t1.w = odd ? a.w : sz;
      }
      {
        float sx = __shfl_xor(t1.x, 2), sy = __shfl_xor(t1.y, 2);
        float sz = __shfl_xor(t1.z, 2), sw = __shfl_xor(t1.w, 2);
        bool hi = q & 2;
        t2.x = hi ? sz : t1.x;  t2.y = hi ? sw : t1.y;
        t2.z = hi ? t1.z : sx;  t2.w = hi ? t1.w : sy;
      }
      // lane now holds px_local=q, ic = 4Q..4Q+3 (component j = ic 4Q+j)
      f16x4 h = { (f16)t2.x, (f16)t2.y, (f16)t2.z, (f16)t2.w };
      *(f16x4*)(smem + sr * ROWB + (g * 4 + q + 1) * PADB + Q * 8) = h;
    }
  }
  __syncthreads();

  const int wv = tid >> 6, l = tid & 63;
  const int rp = wv >> 2;                // pooled row within block (0..1)
  const int pxb = (wv & 3) * 32;
  const int rl0 = rp * 2;
  const int lp = l & 15, kg = l >> 4;

  f16x8 A[5][2];
#pragma unroll
  for (int ks = 0; ks < 5; ++ks)
#pragma unroll
    for (int og = 0; og < 2; ++og)
      A[ks][og] = *(const f16x8*)(apack + (((ks * 2 + og) << 9) + (l << 3)));

  f32x4 acc[2][2][2];
#pragma unroll
  for (int a = 0; a < 2; ++a)
#pragma unroll
    for (int b = 0; b < 2; ++b)
#pragma unroll
      for (int c = 0; c < 2; ++c)
        acc[a][b][c] = (f32x4){0.f, 0.f, 0.f, 0.f};

#pragma unroll
  for (int rowi = 0; rowi < 2; ++rowi) {
#pragma unroll
    for (int pg = 0; pg < 2; ++pg) {
      const int p = pxb + pg * 16 + lp;
#pragma unroll
      for (int ks = 0; ks < 5; ++ks) {
        // k-octet q8 = ks*4+kg -> (kh, kw, ichalf); k = kh*48 + kw*16 + ic
        const int q8 = ks * 4 + kg;
        const int kh = q8 / 6;
        const int t6 = q8 - kh * 6;
        const int kw = t6 >> 1;
        const int ichalf = t6 & 1;
        const int slot = rl0 + rowi + kh;          // <= 6 (kh=3 octets have A=0)
        f16x8 B = *(const f16x8*)(smem + slot * ROWB + (p + kw) * PADB + ichalf * 16);
#pragma unroll
        for (int og = 0; og < 2; ++og)
          acc[rowi][pg][og] =
              __builtin_amdgcn_mfma_f32_16x16x32_f16(A[ks][og], B, acc[rowi][pg][og], 0, 0, 0);
      }
    }
  }
  // epilogue: pool 2x2, bias, relu, NHWC f16 store (OC=32)
  const int pr = blockIdx.x * 2 + rp;
#pragma unroll
  for (int pg = 0; pg < 2; ++pg) {
#pragma unroll
    for (int og = 0; og < 2; ++og) {
      float v[4];
#pragma unroll
      for (int c = 0; c < 4; ++c) {
        float m = fmaxf(acc[0][pg][og][c], acc[1][pg][og][c]);
        v[c] = fmaxf(m, __shfl_xor(m, 1));
      }
      if ((l & 1) == 0) {
        const int pw = (pxb + pg * 16 + lp) >> 1;
        const int oc0 = og * 16 + kg * 4;
        f16x4 pk;
#pragma unroll
        for (int c = 0; c < 4; ++c)
          pk[c] = (f16)fmaxf(v[c] + bias[oc0 + c], 0.f);
        *(f16x4*)(hout + (((size_t)(n * 64 + pr) * 64 + pw) * 32 + oc0)) = pk;
      }
    }
  }
}

// ---------------- conv2/3/4: NHWC f16 -> NHWC f16 (or NCHW f32), pool ----------
template<int C, int W, int H, int BR, int KS, int PADB, int PGn, bool NCHW_OUT>
__global__ __launch_bounds__(256)
void conv_shift(const f16* __restrict__ hin, const f16* __restrict__ apack,
                const float* __restrict__ bias, void* __restrict__ hout) {
  constexpr int SR = BR + 2;
  constexpr int ROWB = (W + 2) * PADB;
  __shared__ char smem[SR * ROWB];
  const int tid = threadIdx.x;
  const int n = blockIdx.y;
  const int r0 = blockIdx.x * BR;
  constexpr int CPC = C / 8;
  constexpr int TOTC = SR * (W + 2) * CPC;
  for (int t = tid; t < TOTC; t += 256) {
    int sr = t / ((W + 2) * CPC);
    int rem = t - sr * ((W + 2) * CPC);
    int px = rem / CPC;
    int kc = rem - px * CPC;
    int ri = r0 + sr - 1;
    int gx = px - 1;
    float4 v = make_float4(0.f, 0.f, 0.f, 0.f);
    if (ri >= 0 && ri < H && gx >= 0 && gx < W)
      v = *(const float4*)(hin + (((size_t)(n * H + ri) * W + gx) * C + kc * 8));
    *(float4*)(smem + sr * ROWB + px * PADB + kc * 16) = v;
  }
  __syncthreads();

  const int wv = tid >> 6, l = tid & 63;
  constexpr int WPP = W / (16 * PGn);
  const int rp = wv / WPP;
  const int pxb = (wv % WPP) * 16 * PGn;
  const int rl0 = rp * 2;
  const int lp = l & 15, kg = l >> 4;
  const int px0 = pxb + lp;

  f32x4 acc[2][PGn][4];
#pragma unroll
  for (int a = 0; a < 2; ++a)
#pragma unroll
    for (int b = 0; b < PGn; ++b)
#pragma unroll
      for (int c = 0; c < 4; ++c)
        acc[a][b][c] = (f32x4){0.f, 0.f, 0.f, 0.f};

  for (int sh = 0; sh < 9; ++sh) {
    const int kh = sh / 3, kw = sh % 3;
    f16x8 A[KS][4];
#pragma unroll
    for (int ks = 0; ks < KS; ++ks)
#pragma unroll
      for (int og = 0; og < 4; ++og)
        A[ks][og] = *(const f16x8*)(apack + ((((sh * KS + ks) * 4 + og) << 9) + (l << 3)));
#pragma unroll
    for (int rowi = 0; rowi < 2; ++rowi) {
      const char* base = smem + (rl0 + rowi + kh) * ROWB;
#pragma unroll
      for (int pg = 0; pg < PGn; ++pg) {
#pragma unroll
        for (int ks = 0; ks < KS; ++ks) {
          f16x8 B = *(const f16x8*)(base + (px0 + pg * 16 + kw) * PADB + ks * 64 + kg * 16);
#pragma unroll
          for (int og = 0; og < 4; ++og)
            acc[rowi][pg][og] =
                __builtin_amdgcn_mfma_f32_16x16x32_f16(A[ks][og], B, acc[rowi][pg][og], 0, 0, 0);
        }
      }
    }
  }
  constexpr int PH = H / 2, PW = W / 2;
  const int pr = blockIdx.x * (BR / 2) + rp;
#pragma unroll
  for (int pg = 0; pg < PGn; ++pg) {
#pragma unroll
    for (int og = 0; og < 4; ++og) {
      float v[4];
#pragma unroll
      for (int c = 0; c < 4; ++c) {
        float m = fmaxf(acc[0][pg][og][c], acc[1][pg][og][c]);
        v[c] = fmaxf(m, __shfl_xor(m, 1));
      }
      if ((l & 1) == 0) {
        const int pw = (pxb + pg * 16 + lp) >> 1;
        const int oc0 = og * 16 + kg * 4;
        if constexpr (NCHW_OUT) {
          float* o = (float*)hout;
#pragma unroll
          for (int c = 0; c < 4; ++c)
            o[(((size_t)n * 64 + oc0 + c) * PH + pr) * PW + pw] =
                fmaxf(v[c] + bias[oc0 + c], 0.f);
        } else {
          f16x4 pk;
#pragma unroll
          for (int c = 0; c < 4; ++c)
            pk[c] = (f16)fmaxf(v[c] + bias[oc0 + c], 0.f);
          *(f16x4*)((f16*)hout + (((size_t)(n * PH + pr) * PW + pw) * 64 + oc0)) = pk;
        }
      }
    }
  }
}

// ---------------- FC head: 2 batch rows/block, 8-way K-split, 1024 thr --------
// scan collapses: fx = h.(wl2[0]+20*wl2[2]) + bl2[0]+20*bl2[2]
__global__ __launch_bounds__(1024)
void fc_head(const float* __restrict__ h4, const float* __restrict__ wl1,
             const float* __restrict__ bl1, const float* __restrict__ wl2,
             const float* __restrict__ bl2, float* __restrict__ out) {
  __shared__ float rows[2][4096];
  __shared__ float red[8 * 128 * 2];
  __shared__ float red2[2 * 128];
  const int tid = threadIdx.x;
  const int b0 = blockIdx.x * 2;
  {
    const float4* src = (const float4*)(h4 + (size_t)b0 * 4096);
    float4* dst = (float4*)rows;
    for (int t = tid; t < 2048; t += 1024) dst[t] = src[t];
  }
  __syncthreads();

  const int nn = tid & 127;
  const int ks = tid >> 7;                 // 0..7, 512 K each
  const float4* wp = (const float4*)(wl1 + (size_t)nn * 4096 + ks * 512);
  const float4* x0 = (const float4*)(&rows[0][ks * 512]);
  const float4* x1 = (const float4*)(&rows[1][ks * 512]);
  float s0 = 0.f, s1 = 0.f;
#pragma unroll 8
  for (int i = 0; i < 128; ++i) {
    float4 w = wp[i], a = x0[i], b = x1[i];
    s0 = fmaf(w.x, a.x, fmaf(w.y, a.y, fmaf(w.z, a.z, fmaf(w.w, a.w, s0))));
    s1 = fmaf(w.x, b.x, fmaf(w.y, b.y, fmaf(w.z, b.z, fmaf(w.w, b.w, s1))));
  }
  red[(ks * 128 + nn) * 2 + 0] = s0;
  red[(ks * 128 + nn) * 2 + 1] = s1;
  __syncthreads();

  if (tid < 256) {
    const int r = tid >> 7, n2 = tid & 127;
    float h = bl1[n2];
#pragma unroll
    for (int k = 0; k < 8; ++k) h += red[(k * 128 + n2) * 2 + r];
    h = fmaxf(h, 0.f);
    red2[r * 128 + n2] = h * (wl2[n2] + 20.0f * wl2[256 + n2]);
  }
  __syncthreads();
#pragma unroll
  for (int s = 64; s > 0; s >>= 1) {
    if (tid < 2 * s) {
      int r = tid / s, i = tid - r * s;
      red2[r * 128 + i] += red2[r * 128 + i + s];
    }
    __syncthreads();
  }
  if (tid < 2) out[b0 + tid] = red2[tid * 128] + bl2[0] + 20.0f * bl2[2];
}

extern "C" void kernel_launch(void* const* d_in, const int* in_sizes, int n_in,
                              void* d_out, int out_size, void* d_ws, size_t ws_size,
                              hipStream_t stream) {
  const float* x   = (const float*)d_in[0];
  const float* w1  = (const float*)d_in[1];
  const float* b1  = (const float*)d_in[2];
  const float* w2  = (const float*)d_in[3];
  const float* b2  = (const float*)d_in[4];
  const float* w3  = (const float*)d_in[5];
  const float* b3  = (const float*)d_in[6];
  const float* w4  = (const float*)d_in[7];
  const float* b4  = (const float*)d_in[8];
  const float* wl1 = (const float*)d_in[9];
  const float* bl1 = (const float*)d_in[10];
  const float* wl2 = (const float*)d_in[11];
  const float* bl2 = (const float*)d_in[12];
  float* out = (float*)d_out;
  char* ws = (char*)d_ws;

  f16* apack = (f16*)ws;
  f16* h1 = (f16*)(ws + (1u << 20));
  f16* h2 = (f16*)(ws + 68157440u);
  f16* h3 = (f16*)(ws + 101711872u);
  float* h4 = (float*)(ws + 110100480u);

  pack_weights<<<190, 512, 0, stream>>>(w1, w2, w3, w4, apack);
  conv1_mfma<<<dim3(32, 256), 512, 0, stream>>>(x, apack, b1, h1);
  conv_shift<32, 64, 64, 4, 1, 64, 2, false><<<dim3(16, 256), 256, 0, stream>>>(
      h1, apack + 10 * 512, b2, (void*)h2);
  conv_shift<64, 32, 32, 8, 2, 144, 2, false><<<dim3(4, 256), 256, 0, stream>>>(
      h2, apack + 46 * 512, b3, (void*)h3);
  conv_shift<64, 16, 16, 8, 2, 144, 1, true><<<dim3(2, 256), 256, 0, stream>>>(
      h3, apack + 118 * 512, b4, (void*)h4);
  fc_head<<<128, 1024, 0, stream>>>(h4, wl1, bl1, wl2, bl2, out);
}

// Round 7
// 278.352 us; speedup vs baseline: 5.4265x; 1.0907x over previous
//
#include <hip/hip_runtime.h>

// MFMA f16 conv pipeline, round 7.
// Round-6 post-mortem: bank conflicts fixed (8.4e7 -> 7.1e6) but conv1 still
// 168us with MfmaUtil 10.5 / VALUBusy 27 / HBM 18% => latency-bound. Cause:
// staging loops are serial load->shuffle->ds_write chains (7-10 x ~900cyc HBM
// latency per block). Fix: two-phase staging — issue ALL global loads into a
// register array first (pipelined, one latency), then transpose/write to LDS.
//
// mfma_f32_16x16x32_f16 layouts (CDNA4):
//   A[m][k]: m = lane&15, k = (lane>>4)*8 + j
//   B[k][n]: n = lane&15, k = (lane>>4)*8 + j
//   D[m][n]: n = lane&15, m = (lane>>4)*4 + reg
// conv1: full-im2col k=160 (kh*48 + kw*16 + ic, ic padded 12->16, k>=144 zero).
// conv2-4: 9 shifted GEMMs (k=ic).

typedef _Float16 f16;
typedef _Float16 f16x8 __attribute__((ext_vector_type(8)));
typedef _Float16 f16x4 __attribute__((ext_vector_type(4)));
typedef float f32x4 __attribute__((ext_vector_type(4)));

// ---------------- weight pre-pack ----------------
__global__ __launch_bounds__(512)
void pack_weights(const float* __restrict__ w1, const float* __restrict__ w2,
                  const float* __restrict__ w3, const float* __restrict__ w4,
                  f16* __restrict__ apack) {
  int idx = blockIdx.x * 512 + threadIdx.x;   // 190*512 total
  int frag = idx >> 9;
  int e = idx & 511;
  int lane = e >> 3, j = e & 7;
  int row16 = lane & 15, kg = lane >> 4;
  float v = 0.f;
  if (frag < 10) {
    int ks = frag >> 1, og = frag & 1;
    int oc = og * 16 + row16;
    int k = ks * 32 + kg * 8 + j;
    if (k < 144) {
      int kh = k / 48, rem = k % 48, kw = rem >> 4, ic = rem & 15;
      if (ic < 12) v = w1[((oc * 12 + ic) * 3 + kh) * 3 + kw];
    }
  } else if (frag < 46) {
    int f = frag - 10;
    int sh = f >> 2, og = f & 3;
    int kh = sh / 3, kw = sh % 3;
    int oc = og * 16 + row16;
    int ic = kg * 8 + j;
    v = w2[((oc * 32 + ic) * 3 + kh) * 3 + kw];
  } else {
    const float* w = (frag < 118) ? w3 : w4;
    int f = frag - ((frag < 118) ? 46 : 118);
    int sk = f >> 2, og = f & 3;
    int sh = sk >> 1, ks = sk & 1;
    int kh = sh / 3, kw = sh % 3;
    int oc = og * 16 + row16;
    int ic = ks * 32 + kg * 8 + j;
    v = w[((oc * 64 + ic) * 3 + kh) * 3 + kw];
  }
  apack[idx] = (f16)v;
}

// ---------------- conv1: 12ch fp32 NCHW -> 32ch NHWC f16, pool ----------------
// Block: 4 conv rows x 128 px, 512 threads (8 waves; wave: 2 conv rows x 32 px).
// Staging phase 1: all 7 row loads into regs (pipelined). Phase 2: 4x4 quad
// shuffle-transpose + conflict-free ds_write_b64. Pixel stride 48B.
__global__ __launch_bounds__(512)
void conv1_mfma(const float* __restrict__ x, const f16* __restrict__ apack,
                const float* __restrict__ bias, f16* __restrict__ hout) {
  constexpr int W = 128, H = 128;
  constexpr int SR = 7, PADB = 48, ROWB = 130 * PADB;  // 6240 B/row-slot
  __shared__ char smem[SR * ROWB];                     // 43680 B
  const int tid = threadIdx.x;
  const int n = blockIdx.y;
  const int r0 = blockIdx.x * 4;

  // zero halo columns (px 0 and 129) only; everything else gets written
  if (tid < 42) {
    int slot = tid / 6, r = tid % 6;
    int px = (r >= 3) ? 129 : 0;
    int ch = r % 3;
    *(float4*)(smem + slot * ROWB + px * PADB + ch * 16) =
        make_float4(0.f, 0.f, 0.f, 0.f);
  }
  // staging: group g (=tid>>4) owns px chunk g (4 px) for all 7 row-slots.
  {
    const int g = tid >> 4;
    const int l16 = tid & 15;
    const int Q = l16 >> 2, q = l16 & 3;     // quad, lane-in-quad
    float4 a[SR];
#pragma unroll
    for (int sr = 0; sr < SR; ++sr) {        // phase 1: issue all loads
      const int ri = r0 + sr - 1;
      a[sr] = make_float4(0.f, 0.f, 0.f, 0.f);
      if (l16 < 12 && ri >= 0 && ri < H)
        a[sr] = *(const float4*)(x + ((size_t)(n * 12 + l16) * H + ri) * W + g * 4);
    }
#pragma unroll
    for (int sr = 0; sr < SR; ++sr) {        // phase 2: transpose + write
      float4 t1, t2;
      {
        float sx = __shfl_xor(a[sr].x, 1), sy = __shfl_xor(a[sr].y, 1);
        float sz = __shfl_xor(a[sr].z, 1), sw = __shfl_xor(a[sr].w, 1);
        bool odd = q & 1;
        t1.x = odd ? sy : a[sr].x;  t1.y = odd ? a[sr].y : sx;
        t1.z = odd ? sw : a[sr].z;  t1.w = odd ? a[sr].w : sz;
      }
      {
        float sx = __shfl_xor(t1.x, 2), sy = __shfl_xor(t1.y, 2);
        float sz = __shfl_xor(t1.z, 2), sw = __shfl_xor(t1.w, 2);
        bool hi = q & 2;
        t2.x = hi ? sz : t1.x;  t2.y = hi ? sw : t1.y;
        t2.z = hi ? t1.z : sx;  t2.w = hi ? t1.w : sy;
      }
      f16x4 h = { (f16)t2.x, (f16)t2.y, (f16)t2.z, (f16)t2.w };
      *(f16x4*)(smem + sr * ROWB + (g * 4 + q + 1) * PADB + Q * 8) = h;
    }
  }
  __syncthreads();

  const int wv = tid >> 6, l = tid & 63;
  const int rp = wv >> 2;                // pooled row within block (0..1)
  const int pxb = (wv & 3) * 32;
  const int rl0 = rp * 2;
  const int lp = l & 15, kg = l >> 4;

  f16x8 A[5][2];
#pragma unroll
  for (int ks = 0; ks < 5; ++ks)
#pragma unroll
    for (int og = 0; og < 2; ++og)
      A[ks][og] = *(const f16x8*)(apack + (((ks * 2 + og) << 9) + (l << 3)));

  f32x4 acc[2][2][2];
#pragma unroll
  for (int a = 0; a < 2; ++a)
#pragma unroll
    for (int b = 0; b < 2; ++b)
#pragma unroll
      for (int c = 0; c < 2; ++c)
        acc[a][b][c] = (f32x4){0.f, 0.f, 0.f, 0.f};

#pragma unroll
  for (int rowi = 0; rowi < 2; ++rowi) {
#pragma unroll
    for (int pg = 0; pg < 2; ++pg) {
      const int p = pxb + pg * 16 + lp;
#pragma unroll
      for (int ks = 0; ks < 5; ++ks) {
        // k-octet q8 = ks*4+kg -> (kh, kw, ichalf); k = kh*48 + kw*16 + ic
        const int q8 = ks * 4 + kg;
        const int kh = q8 / 6;
        const int t6 = q8 - kh * 6;
        const int kw = t6 >> 1;
        const int ichalf = t6 & 1;
        const int slot = rl0 + rowi + kh;          // <= 6 (kh=3 octets have A=0)
        f16x8 B = *(const f16x8*)(smem + slot * ROWB + (p + kw) * PADB + ichalf * 16);
#pragma unroll
        for (int og = 0; og < 2; ++og)
          acc[rowi][pg][og] =
              __builtin_amdgcn_mfma_f32_16x16x32_f16(A[ks][og], B, acc[rowi][pg][og], 0, 0, 0);
      }
    }
  }
  // epilogue: pool 2x2, bias, relu, NHWC f16 store (OC=32)
  const int pr = blockIdx.x * 2 + rp;
#pragma unroll
  for (int pg = 0; pg < 2; ++pg) {
#pragma unroll
    for (int og = 0; og < 2; ++og) {
      float v[4];
#pragma unroll
      for (int c = 0; c < 4; ++c) {
        float m = fmaxf(acc[0][pg][og][c], acc[1][pg][og][c]);
        v[c] = fmaxf(m, __shfl_xor(m, 1));
      }
      if ((l & 1) == 0) {
        const int pw = (pxb + pg * 16 + lp) >> 1;
        const int oc0 = og * 16 + kg * 4;
        f16x4 pk;
#pragma unroll
        for (int c = 0; c < 4; ++c)
          pk[c] = (f16)fmaxf(v[c] + bias[oc0 + c], 0.f);
        *(f16x4*)(hout + (((size_t)(n * 64 + pr) * 64 + pw) * 32 + oc0)) = pk;
      }
    }
  }
}

// ---------------- conv2/3/4: NHWC f16 -> NHWC f16 (or NCHW f32), pool ----------
template<int C, int W, int H, int BR, int KS, int PADB, int PGn, bool NCHW_OUT>
__global__ __launch_bounds__(256)
void conv_shift(const f16* __restrict__ hin, const f16* __restrict__ apack,
                const float* __restrict__ bias, void* __restrict__ hout) {
  constexpr int SR = BR + 2;
  constexpr int ROWB = (W + 2) * PADB;
  __shared__ char smem[SR * ROWB];
  const int tid = threadIdx.x;
  const int n = blockIdx.y;
  const int r0 = blockIdx.x * BR;
  constexpr int CPC = C / 8;
  constexpr int TOTC = SR * (W + 2) * CPC;
  constexpr int NITER = (TOTC + 255) / 256;
  {
    float4 stg[NITER];
#pragma unroll
    for (int it = 0; it < NITER; ++it) {     // phase 1: issue all loads
      const int t = tid + it * 256;
      float4 v = make_float4(0.f, 0.f, 0.f, 0.f);
      if (t < TOTC) {
        int sr = t / ((W + 2) * CPC);
        int rem = t - sr * ((W + 2) * CPC);
        int px = rem / CPC;
        int kc = rem - px * CPC;
        int ri = r0 + sr - 1;
        int gx = px - 1;
        if (ri >= 0 && ri < H && gx >= 0 && gx < W)
          v = *(const float4*)(hin + (((size_t)(n * H + ri) * W + gx) * C + kc * 8));
      }
      stg[it] = v;
    }
#pragma unroll
    for (int it = 0; it < NITER; ++it) {     // phase 2: write to LDS
      const int t = tid + it * 256;
      if (t < TOTC) {
        int sr = t / ((W + 2) * CPC);
        int rem = t - sr * ((W + 2) * CPC);
        int px = rem / CPC;
        int kc = rem - px * CPC;
        *(float4*)(smem + sr * ROWB + px * PADB + kc * 16) = stg[it];
      }
    }
  }
  __syncthreads();

  const int wv = tid >> 6, l = tid & 63;
  constexpr int WPP = W / (16 * PGn);
  const int rp = wv / WPP;
  const int pxb = (wv % WPP) * 16 * PGn;
  const int rl0 = rp * 2;
  const int lp = l & 15, kg = l >> 4;
  const int px0 = pxb + lp;

  f32x4 acc[2][PGn][4];
#pragma unroll
  for (int a = 0; a < 2; ++a)
#pragma unroll
    for (int b = 0; b < PGn; ++b)
#pragma unroll
      for (int c = 0; c < 4; ++c)
        acc[a][b][c] = (f32x4){0.f, 0.f, 0.f, 0.f};

  for (int sh = 0; sh < 9; ++sh) {
    const int kh = sh / 3, kw = sh % 3;
    f16x8 A[KS][4];
#pragma unroll
    for (int ks = 0; ks < KS; ++ks)
#pragma unroll
      for (int og = 0; og < 4; ++og)
        A[ks][og] = *(const f16x8*)(apack + ((((sh * KS + ks) * 4 + og) << 9) + (l << 3)));
#pragma unroll
    for (int rowi = 0; rowi < 2; ++rowi) {
      const char* base = smem + (rl0 + rowi + kh) * ROWB;
#pragma unroll
      for (int pg = 0; pg < PGn; ++pg) {
#pragma unroll
        for (int ks = 0; ks < KS; ++ks) {
          f16x8 B = *(const f16x8*)(base + (px0 + pg * 16 + kw) * PADB + ks * 64 + kg * 16);
#pragma unroll
          for (int og = 0; og < 4; ++og)
            acc[rowi][pg][og] =
                __builtin_amdgcn_mfma_f32_16x16x32_f16(A[ks][og], B, acc[rowi][pg][og], 0, 0, 0);
        }
      }
    }
  }
  constexpr int PH = H / 2, PW = W / 2;
  const int pr = blockIdx.x * (BR / 2) + rp;
#pragma unroll
  for (int pg = 0; pg < PGn; ++pg) {
#pragma unroll
    for (int og = 0; og < 4; ++og) {
      float v[4];
#pragma unroll
      for (int c = 0; c < 4; ++c) {
        float m = fmaxf(acc[0][pg][og][c], acc[1][pg][og][c]);
        v[c] = fmaxf(m, __shfl_xor(m, 1));
      }
      if ((l & 1) == 0) {
        const int pw = (pxb + pg * 16 + lp) >> 1;
        const int oc0 = og * 16 + kg * 4;
        if constexpr (NCHW_OUT) {
          float* o = (float*)hout;
#pragma unroll
          for (int c = 0; c < 4; ++c)
            o[(((size_t)n * 64 + oc0 + c) * PH + pr) * PW + pw] =
                fmaxf(v[c] + bias[oc0 + c], 0.f);
        } else {
          f16x4 pk;
#pragma unroll
          for (int c = 0; c < 4; ++c)
            pk[c] = (f16)fmaxf(v[c] + bias[oc0 + c], 0.f);
          *(f16x4*)((f16*)hout + (((size_t)(n * PH + pr) * PW + pw) * 64 + oc0)) = pk;
        }
      }
    }
  }
}

// ---------------- FC head: 2 batch rows/block, 8-way K-split, 1024 thr --------
// scan collapses: fx = h.(wl2[0]+20*wl2[2]) + bl2[0]+20*bl2[2]
__global__ __launch_bounds__(1024)
void fc_head(const float* __restrict__ h4, const float* __restrict__ wl1,
             const float* __restrict__ bl1, const float* __restrict__ wl2,
             const float* __restrict__ bl2, float* __restrict__ out) {
  __shared__ float rows[2][4096];
  __shared__ float red[8 * 128 * 2];
  __shared__ float red2[2 * 128];
  const int tid = threadIdx.x;
  const int b0 = blockIdx.x * 2;
  {
    const float4* src = (const float4*)(h4 + (size_t)b0 * 4096);
    float4* dst = (float4*)rows;
    for (int t = tid; t < 2048; t += 1024) dst[t] = src[t];
  }
  __syncthreads();

  const int nn = tid & 127;
  const int ks = tid >> 7;                 // 0..7, 512 K each
  const float4* wp = (const float4*)(wl1 + (size_t)nn * 4096 + ks * 512);
  const float4* x0 = (const float4*)(&rows[0][ks * 512]);
  const float4* x1 = (const float4*)(&rows[1][ks * 512]);
  float s0 = 0.f, s1 = 0.f;
#pragma unroll 8
  for (int i = 0; i < 128; ++i) {
    float4 w = wp[i], a = x0[i], b = x1[i];
    s0 = fmaf(w.x, a.x, fmaf(w.y, a.y, fmaf(w.z, a.z, fmaf(w.w, a.w, s0))));
    s1 = fmaf(w.x, b.x, fmaf(w.y, b.y, fmaf(w.z, b.z, fmaf(w.w, b.w, s1))));
  }
  red[(ks * 128 + nn) * 2 + 0] = s0;
  red[(ks * 128 + nn) * 2 + 1] = s1;
  __syncthreads();

  if (tid < 256) {
    const int r = tid >> 7, n2 = tid & 127;
    float h = bl1[n2];
#pragma unroll
    for (int k = 0; k < 8; ++k) h += red[(k * 128 + n2) * 2 + r];
    h = fmaxf(h, 0.f);
    red2[r * 128 + n2] = h * (wl2[n2] + 20.0f * wl2[256 + n2]);
  }
  __syncthreads();
#pragma unroll
  for (int s = 64; s > 0; s >>= 1) {
    if (tid < 2 * s) {
      int r = tid / s, i = tid - r * s;
      red2[r * 128 + i] += red2[r * 128 + i + s];
    }
    __syncthreads();
  }
  if (tid < 2) out[b0 + tid] = red2[tid * 128] + bl2[0] + 20.0f * bl2[2];
}

extern "C" void kernel_launch(void* const* d_in, const int* in_sizes, int n_in,
                              void* d_out, int out_size, void* d_ws, size_t ws_size,
                              hipStream_t stream) {
  const float* x   = (const float*)d_in[0];
  const float* w1  = (const float*)d_in[1];
  const float* b1  = (const float*)d_in[2];
  const float* w2  = (const float*)d_in[3];
  const float* b2  = (const float*)d_in[4];
  const float* w3  = (const float*)d_in[5];
  const float* b3  = (const float*)d_in[6];
  const float* w4  = (const float*)d_in[7];
  const float* b4  = (const float*)d_in[8];
  const float* wl1 = (const float*)d_in[9];
  const float* bl1 = (const float*)d_in[10];
  const float* wl2 = (const float*)d_in[11];
  const float* bl2 = (const float*)d_in[12];
  float* out = (float*)d_out;
  char* ws = (char*)d_ws;

  f16* apack = (f16*)ws;
  f16* h1 = (f16*)(ws + (1u << 20));
  f16* h2 = (f16*)(ws + 68157440u);
  f16* h3 = (f16*)(ws + 101711872u);
  float* h4 = (float*)(ws + 110100480u);

  pack_weights<<<190, 512, 0, stream>>>(w1, w2, w3, w4, apack);
  conv1_mfma<<<dim3(32, 256), 512, 0, stream>>>(x, apack, b1, h1);
  conv_shift<32, 64, 64, 4, 1, 64, 2, false><<<dim3(16, 256), 256, 0, stream>>>(
      h1, apack + 10 * 512, b2, (void*)h2);
  conv_shift<64, 32, 32, 8, 2, 144, 2, false><<<dim3(4, 256), 256, 0, stream>>>(
      h2, apack + 46 * 512, b3, (void*)h3);
  conv_shift<64, 16, 16, 8, 2, 144, 1, true><<<dim3(2, 256), 256, 0, stream>>>(
      h3, apack + 118 * 512, b4, (void*)h4);
  fc_head<<<128, 1024, 0, stream>>>(h4, wl1, bl1, wl2, bl2, out);
}

// Round 8
// 242.977 us; speedup vs baseline: 6.2166x; 1.1456x over previous
//
#include <hip/hip_runtime.h>

// MFMA f16 conv pipeline, round 8.
// Round-7 post-mortem: conv1 latency-bound; compute phase was 1:1
// ds_read_b128:MFMA (LDS pipe ~10x the MFMA cycles), k=160 im2col 1.48x
// padded, 7th staged row only fed zero weights. Fix: conv1 via
// mfma_f32_32x32x16_f16, k=144 = 9 (kh,kw) slices x 16 ic. 18 reads + 18
// MFMA per wave, SR 7->6 (37.4KB LDS -> 4 blocks/CU), 6 staged rows.
//
// Layouts (CDNA4):
//   16x16x32: A/B k = (lane>>4)*8+j, m/n = lane&15; D col=lane&15, row=(lane>>4)*4+reg
//   32x32x16: A/B k = (lane>>5)*8+j, m/n = lane&31; D col=lane&31,
//             row=(reg&3)+8*(reg>>2)+4*(lane>>5)
// conv2-4: 9 shifted GEMMs (k=ic), 16x16x32, unchanged.

typedef _Float16 f16;
typedef _Float16 f16x8 __attribute__((ext_vector_type(8)));
typedef _Float16 f16x4 __attribute__((ext_vector_type(4)));
typedef float f32x4 __attribute__((ext_vector_type(4)));
typedef float f32x16 __attribute__((ext_vector_type(16)));

// ---------------- weight pre-pack ----------------
// frags (1024B = [lane][j] f16): conv1: 9 (32x32 A, ks=kh*3+kw); conv2: 36 @9;
// conv3: 72 @45; conv4: 72 @117. Total 189.
__global__ __launch_bounds__(512)
void pack_weights(const float* __restrict__ w1, const float* __restrict__ w2,
                  const float* __restrict__ w3, const float* __restrict__ w4,
                  f16* __restrict__ apack) {
  int idx = blockIdx.x * 512 + threadIdx.x;   // 189*512 total
  int frag = idx >> 9;
  int e = idx & 511;
  int lane = e >> 3, j = e & 7;
  float v = 0.f;
  if (frag < 9) {
    // conv1 32x32x16 A-frag: m(oc) = lane&31, k(ic) = (lane>>5)*8 + j
    int kh = frag / 3, kw = frag % 3;
    int oc = lane & 31;
    int ic = (lane >> 5) * 8 + j;
    if (ic < 12) v = w1[((oc * 12 + ic) * 3 + kh) * 3 + kw];
  } else if (frag < 45) {
    int f = frag - 9;
    int sh = f >> 2, og = f & 3;
    int kh = sh / 3, kw = sh % 3;
    int row16 = lane & 15, kg = lane >> 4;
    int oc = og * 16 + row16;
    int ic = kg * 8 + j;
    v = w2[((oc * 32 + ic) * 3 + kh) * 3 + kw];
  } else {
    const float* w = (frag < 117) ? w3 : w4;
    int f = frag - ((frag < 117) ? 45 : 117);
    int sk = f >> 2, og = f & 3;
    int sh = sk >> 1, ks = sk & 1;
    int kh = sh / 3, kw = sh % 3;
    int row16 = lane & 15, kg = lane >> 4;
    int oc = og * 16 + row16;
    int ic = ks * 32 + kg * 8 + j;
    v = w[((oc * 64 + ic) * 3 + kh) * 3 + kw];
  }
  apack[idx] = (f16)v;
}

// ---------------- conv1: 12ch fp32 NCHW -> 32ch NHWC f16, pool ----------------
// Block: 4 conv rows x 128 px, 512 threads (8 waves; wave: 2 conv rows x 32 px,
// 32x32x16 MFMA covers all 32 oc). Staging: all 6 row loads into regs
// (pipelined), then 4x4 quad shuffle-transpose + ds_write_b64.
__global__ __launch_bounds__(512)
void conv1_mfma(const float* __restrict__ x, const f16* __restrict__ apack,
                const float* __restrict__ bias, f16* __restrict__ hout) {
  constexpr int W = 128, H = 128;
  constexpr int SR = 6, PADB = 48, ROWB = 130 * PADB;  // 6240 B/row-slot
  __shared__ char smem[SR * ROWB];                     // 37440 B -> 4 blk/CU
  const int tid = threadIdx.x;
  const int n = blockIdx.y;
  const int r0 = blockIdx.x * 4;

  // zero halo columns (px 0 and 129)
  if (tid < 36) {
    int slot = tid / 6, r = tid % 6;
    int px = (r >= 3) ? 129 : 0;
    int ch = r % 3;
    *(float4*)(smem + slot * ROWB + px * PADB + ch * 16) =
        make_float4(0.f, 0.f, 0.f, 0.f);
  }
  // staging: group g (=tid>>4) owns px chunk g (4 px) for all 6 row-slots.
  {
    const int g = tid >> 4;
    const int l16 = tid & 15;
    const int Q = l16 >> 2, q = l16 & 3;     // quad, lane-in-quad
    float4 a[SR];
#pragma unroll
    for (int sr = 0; sr < SR; ++sr) {        // phase 1: issue all loads
      const int ri = r0 + sr - 1;
      a[sr] = make_float4(0.f, 0.f, 0.f, 0.f);
      if (l16 < 12 && ri >= 0 && ri < H)
        a[sr] = *(const float4*)(x + ((size_t)(n * 12 + l16) * H + ri) * W + g * 4);
    }
#pragma unroll
    for (int sr = 0; sr < SR; ++sr) {        // phase 2: transpose + write
      float4 t1, t2;
      {
        float sx = __shfl_xor(a[sr].x, 1), sy = __shfl_xor(a[sr].y, 1);
        float sz = __shfl_xor(a[sr].z, 1), sw = __shfl_xor(a[sr].w, 1);
        bool odd = q & 1;
        t1.x = odd ? sy : a[sr].x;  t1.y = odd ? a[sr].y : sx;
        t1.z = odd ? sw : a[sr].z;  t1.w = odd ? a[sr].w : sz;
      }
      {
        float sx = __shfl_xor(t1.x, 2), sy = __shfl_xor(t1.y, 2);
        float sz = __shfl_xor(t1.z, 2), sw = __shfl_xor(t1.w, 2);
        bool hi = q & 2;
        t2.x = hi ? sz : t1.x;  t2.y = hi ? sw : t1.y;
        t2.z = hi ? t1.z : sx;  t2.w = hi ? t1.w : sy;
      }
      f16x4 h = { (f16)t2.x, (f16)t2.y, (f16)t2.z, (f16)t2.w };
      *(f16x4*)(smem + sr * ROWB + (g * 4 + q + 1) * PADB + Q * 8) = h;
    }
  }
  __syncthreads();

  const int wv = tid >> 6, l = tid & 63;
  const int rp = wv >> 2;                // pooled row within block (0..1)
  const int pxb = (wv & 3) * 32;
  const int rl0 = rp * 2;
  const int ln = l & 31;                 // px lane (n of MFMA)
  const int hi = l >> 5;                 // k-half / D row offset

  f16x8 A[9];
#pragma unroll
  for (int ks = 0; ks < 9; ++ks)
    A[ks] = *(const f16x8*)(apack + ((ks << 9) + (l << 3)));

  f32x16 acc[2];
  acc[0] = (f32x16)0.f;
  acc[1] = (f32x16)0.f;

#pragma unroll
  for (int rowi = 0; rowi < 2; ++rowi) {
#pragma unroll
    for (int ks = 0; ks < 9; ++ks) {
      const int kh = ks / 3, kw = ks % 3;
      const int slot = rl0 + rowi + kh;          // <= 5
      f16x8 B = *(const f16x8*)(smem + slot * ROWB + (pxb + ln + kw) * PADB + hi * 16);
      acc[rowi] = __builtin_amdgcn_mfma_f32_32x32x16_f16(A[ks], B, acc[rowi], 0, 0, 0);
    }
  }
  // epilogue: pool 2x2, bias, relu, NHWC f16 store (OC=32)
  // D: px = ln, oc = (reg&3) + 8*(reg>>2) + 4*hi
  const int pr = blockIdx.x * 2 + rp;
#pragma unroll
  for (int g = 0; g < 4; ++g) {
    float v[4];
#pragma unroll
    for (int c = 0; c < 4; ++c) {
      float m = fmaxf(acc[0][g * 4 + c], acc[1][g * 4 + c]);
      v[c] = fmaxf(m, __shfl_xor(m, 1));
    }
    if ((l & 1) == 0) {
      const int pw = (pxb + ln) >> 1;
      const int oc0 = g * 8 + hi * 4;
      f16x4 pk;
#pragma unroll
      for (int c = 0; c < 4; ++c)
        pk[c] = (f16)fmaxf(v[c] + bias[oc0 + c], 0.f);
      *(f16x4*)(hout + (((size_t)(n * 64 + pr) * 64 + pw) * 32 + oc0)) = pk;
    }
  }
}

// ---------------- conv2/3/4: NHWC f16 -> NHWC f16 (or NCHW f32), pool ----------
template<int C, int W, int H, int BR, int KS, int PADB, int PGn, bool NCHW_OUT>
__global__ __launch_bounds__(256)
void conv_shift(const f16* __restrict__ hin, const f16* __restrict__ apack,
                const float* __restrict__ bias, void* __restrict__ hout) {
  constexpr int SR = BR + 2;
  constexpr int ROWB = (W + 2) * PADB;
  __shared__ char smem[SR * ROWB];
  const int tid = threadIdx.x;
  const int n = blockIdx.y;
  const int r0 = blockIdx.x * BR;
  constexpr int CPC = C / 8;
  constexpr int TOTC = SR * (W + 2) * CPC;
  constexpr int NITER = (TOTC + 255) / 256;
  {
    float4 stg[NITER];
#pragma unroll
    for (int it = 0; it < NITER; ++it) {     // phase 1: issue all loads
      const int t = tid + it * 256;
      float4 v = make_float4(0.f, 0.f, 0.f, 0.f);
      if (t < TOTC) {
        int sr = t / ((W + 2) * CPC);
        int rem = t - sr * ((W + 2) * CPC);
        int px = rem / CPC;
        int kc = rem - px * CPC;
        int ri = r0 + sr - 1;
        int gx = px - 1;
        if (ri >= 0 && ri < H && gx >= 0 && gx < W)
          v = *(const float4*)(hin + (((size_t)(n * H + ri) * W + gx) * C + kc * 8));
      }
      stg[it] = v;
    }
#pragma unroll
    for (int it = 0; it < NITER; ++it) {     // phase 2: write to LDS
      const int t = tid + it * 256;
      if (t < TOTC) {
        int sr = t / ((W + 2) * CPC);
        int rem = t - sr * ((W + 2) * CPC);
        int px = rem / CPC;
        int kc = rem - px * CPC;
        *(float4*)(smem + sr * ROWB + px * PADB + kc * 16) = stg[it];
      }
    }
  }
  __syncthreads();

  const int wv = tid >> 6, l = tid & 63;
  constexpr int WPP = W / (16 * PGn);
  const int rp = wv / WPP;
  const int pxb = (wv % WPP) * 16 * PGn;
  const int rl0 = rp * 2;
  const int lp = l & 15, kg = l >> 4;
  const int px0 = pxb + lp;

  f32x4 acc[2][PGn][4];
#pragma unroll
  for (int a = 0; a < 2; ++a)
#pragma unroll
    for (int b = 0; b < PGn; ++b)
#pragma unroll
      for (int c = 0; c < 4; ++c)
        acc[a][b][c] = (f32x4){0.f, 0.f, 0.f, 0.f};

  for (int sh = 0; sh < 9; ++sh) {
    const int kh = sh / 3, kw = sh % 3;
    f16x8 A[KS][4];
#pragma unroll
    for (int ks = 0; ks < KS; ++ks)
#pragma unroll
      for (int og = 0; og < 4; ++og)
        A[ks][og] = *(const f16x8*)(apack + ((((sh * KS + ks) * 4 + og) << 9) + (l << 3)));
#pragma unroll
    for (int rowi = 0; rowi < 2; ++rowi) {
      const char* base = smem + (rl0 + rowi + kh) * ROWB;
#pragma unroll
      for (int pg = 0; pg < PGn; ++pg) {
#pragma unroll
        for (int ks = 0; ks < KS; ++ks) {
          f16x8 B = *(const f16x8*)(base + (px0 + pg * 16 + kw) * PADB + ks * 64 + kg * 16);
#pragma unroll
          for (int og = 0; og < 4; ++og)
            acc[rowi][pg][og] =
                __builtin_amdgcn_mfma_f32_16x16x32_f16(A[ks][og], B, acc[rowi][pg][og], 0, 0, 0);
        }
      }
    }
  }
  constexpr int PH = H / 2, PW = W / 2;
  const int pr = blockIdx.x * (BR / 2) + rp;
#pragma unroll
  for (int pg = 0; pg < PGn; ++pg) {
#pragma unroll
    for (int og = 0; og < 4; ++og) {
      float v[4];
#pragma unroll
      for (int c = 0; c < 4; ++c) {
        float m = fmaxf(acc[0][pg][og][c], acc[1][pg][og][c]);
        v[c] = fmaxf(m, __shfl_xor(m, 1));
      }
      if ((l & 1) == 0) {
        const int pw = (pxb + pg * 16 + lp) >> 1;
        const int oc0 = og * 16 + kg * 4;
        if constexpr (NCHW_OUT) {
          float* o = (float*)hout;
#pragma unroll
          for (int c = 0; c < 4; ++c)
            o[(((size_t)n * 64 + oc0 + c) * PH + pr) * PW + pw] =
                fmaxf(v[c] + bias[oc0 + c], 0.f);
        } else {
          f16x4 pk;
#pragma unroll
          for (int c = 0; c < 4; ++c)
            pk[c] = (f16)fmaxf(v[c] + bias[oc0 + c], 0.f);
          *(f16x4*)((f16*)hout + (((size_t)(n * PH + pr) * PW + pw) * 64 + oc0)) = pk;
        }
      }
    }
  }
}

// ---------------- FC head: 2 batch rows/block, 8-way K-split, 1024 thr --------
// scan collapses: fx = h.(wl2[0]+20*wl2[2]) + bl2[0]+20*bl2[2]
__global__ __launch_bounds__(1024)
void fc_head(const float* __restrict__ h4, const float* __restrict__ wl1,
             const float* __restrict__ bl1, const float* __restrict__ wl2,
             const float* __restrict__ bl2, float* __restrict__ out) {
  __shared__ float rows[2][4096];
  __shared__ float red[8 * 128 * 2];
  __shared__ float red2[2 * 128];
  const int tid = threadIdx.x;
  const int b0 = blockIdx.x * 2;
  {
    const float4* src = (const float4*)(h4 + (size_t)b0 * 4096);
    float4* dst = (float4*)rows;
    for (int t = tid; t < 2048; t += 1024) dst[t] = src[t];
  }
  __syncthreads();

  const int nn = tid & 127;
  const int ks = tid >> 7;                 // 0..7, 512 K each
  const float4* wp = (const float4*)(wl1 + (size_t)nn * 4096 + ks * 512);
  const float4* x0 = (const float4*)(&rows[0][ks * 512]);
  const float4* x1 = (const float4*)(&rows[1][ks * 512]);
  float s0 = 0.f, s1 = 0.f;
#pragma unroll 8
  for (int i = 0; i < 128; ++i) {
    float4 w = wp[i], a = x0[i], b = x1[i];
    s0 = fmaf(w.x, a.x, fmaf(w.y, a.y, fmaf(w.z, a.z, fmaf(w.w, a.w, s0))));
    s1 = fmaf(w.x, b.x, fmaf(w.y, b.y, fmaf(w.z, b.z, fmaf(w.w, b.w, s1))));
  }
  red[(ks * 128 + nn) * 2 + 0] = s0;
  red[(ks * 128 + nn) * 2 + 1] = s1;
  __syncthreads();

  if (tid < 256) {
    const int r = tid >> 7, n2 = tid & 127;
    float h = bl1[n2];
#pragma unroll
    for (int k = 0; k < 8; ++k) h += red[(k * 128 + n2) * 2 + r];
    h = fmaxf(h, 0.f);
    red2[r * 128 + n2] = h * (wl2[n2] + 20.0f * wl2[256 + n2]);
  }
  __syncthreads();
#pragma unroll
  for (int s = 64; s > 0; s >>= 1) {
    if (tid < 2 * s) {
      int r = tid / s, i = tid - r * s;
      red2[r * 128 + i] += red2[r * 128 + i + s];
    }
    __syncthreads();
  }
  if (tid < 2) out[b0 + tid] = red2[tid * 128] + bl2[0] + 20.0f * bl2[2];
}

extern "C" void kernel_launch(void* const* d_in, const int* in_sizes, int n_in,
                              void* d_out, int out_size, void* d_ws, size_t ws_size,
                              hipStream_t stream) {
  const float* x   = (const float*)d_in[0];
  const float* w1  = (const float*)d_in[1];
  const float* b1  = (const float*)d_in[2];
  const float* w2  = (const float*)d_in[3];
  const float* b2  = (const float*)d_in[4];
  const float* w3  = (const float*)d_in[5];
  const float* b3  = (const float*)d_in[6];
  const float* w4  = (const float*)d_in[7];
  const float* b4  = (const float*)d_in[8];
  const float* wl1 = (const float*)d_in[9];
  const float* bl1 = (const float*)d_in[10];
  const float* wl2 = (const float*)d_in[11];
  const float* bl2 = (const float*)d_in[12];
  float* out = (float*)d_out;
  char* ws = (char*)d_ws;

  f16* apack = (f16*)ws;
  f16* h1 = (f16*)(ws + (1u << 20));
  f16* h2 = (f16*)(ws + 68157440u);
  f16* h3 = (f16*)(ws + 101711872u);
  float* h4 = (float*)(ws + 110100480u);

  pack_weights<<<189, 512, 0, stream>>>(w1, w2, w3, w4, apack);
  conv1_mfma<<<dim3(32, 256), 512, 0, stream>>>(x, apack, b1, h1);
  conv_shift<32, 64, 64, 4, 1, 64, 2, false><<<dim3(16, 256), 256, 0, stream>>>(
      h1, apack + 9 * 512, b2, (void*)h2);
  conv_shift<64, 32, 32, 8, 2, 144, 2, false><<<dim3(4, 256), 256, 0, stream>>>(
      h2, apack + 45 * 512, b3, (void*)h3);
  conv_shift<64, 16, 16, 8, 2, 144, 1, true><<<dim3(2, 256), 256, 0, stream>>>(
      h3, apack + 117 * 512, b4, (void*)h4);
  fc_head<<<128, 1024, 0, stream>>>(h4, wl1, bl1, wl2, bl2, out);
}